// Round 11
// baseline (2952.584 us; speedup 1.0000x reference)
//
#include <hip/hip_runtime.h>

#define B_ 4
#define T_ 1024
#define D_ 1024
#define H_ 16
#define DH_ 64
#define L_ 12
#define FF_ 4096
#define V_ 8192
#define M_ 4096  // B*T

typedef short bf16x8 __attribute__((ext_vector_type(8)));
typedef unsigned short u16x8 __attribute__((ext_vector_type(8)));
typedef unsigned short u16x4 __attribute__((ext_vector_type(4)));
typedef float f32x4 __attribute__((ext_vector_type(4)));

typedef const __attribute__((address_space(1))) void* gas1;
typedef __attribute__((address_space(3))) void* las3;
#define GL2LDS(g, l) __builtin_amdgcn_global_load_lds((gas1)(g), (las3)(l), 16, 0, 0)
#define MFMA16(a, b, c) __builtin_amdgcn_mfma_f32_16x16x32_bf16((a), (b), (c), 0, 0, 0)
#define WVM(n) asm volatile("s_waitcnt vmcnt(" #n ")" ::: "memory")
#define WLG() asm volatile("s_waitcnt lgkmcnt(0)" ::: "memory")
#define BARRIER() asm volatile("s_barrier" ::: "memory")

static __device__ __forceinline__ unsigned short f2bf(float f) {
  unsigned int u = __builtin_bit_cast(unsigned int, f);
  u += 0x7fffu + ((u >> 16) & 1u);
  return (unsigned short)(u >> 16);
}
static __device__ __forceinline__ float bf2f(unsigned short u) {
  unsigned int v = (unsigned int)u << 16;
  return __builtin_bit_cast(float, v);
}

// T1: bijective XCD swizzle (all grids have gx*gy % 8 == 0)
static __device__ __forceinline__ void xcd_swz(int& bx, int& by) {
  const int gx = gridDim.x;
  const int id = by * gx + bx;
  const int q = (gx * gridDim.y) >> 3;
  const int nid = (id & 7) * q + (id >> 3);
  bx = nid % gx;
  by = nid / gx;
}

// row-LN of an in-register row chunk (4 floats/thread, 256 thr), then bf16 store
static __device__ __forceinline__ void ln_row_store(float4 r, const float* __restrict__ g,
                                                    const float* __restrict__ bb, int row,
                                                    int tid, float* red,
                                                    unsigned short* __restrict__ out) {
  float s = r.x + r.y + r.z + r.w;
  float s2 = r.x * r.x + r.y * r.y + r.z * r.z + r.w * r.w;
#pragma unroll
  for (int off = 32; off; off >>= 1) {
    s += __shfl_down(s, off);
    s2 += __shfl_down(s2, off);
  }
  if ((tid & 63) == 0) { red[tid >> 6] = s; red[4 + (tid >> 6)] = s2; }
  __syncthreads();
  const float ts = red[0] + red[1] + red[2] + red[3];
  const float ts2 = red[4] + red[5] + red[6] + red[7];
  const float mean = ts * (1.f / 1024.f);
  const float var = ts2 * (1.f / 1024.f) - mean * mean;
  const float rstd = rsqrtf(var + 1e-5f);
  const int c = tid * 4;
  u16x4 ov;
  ov[0] = f2bf((r.x - mean) * rstd * g[c] + bb[c]);
  ov[1] = f2bf((r.y - mean) * rstd * g[c + 1] + bb[c + 1]);
  ov[2] = f2bf((r.z - mean) * rstd * g[c + 2] + bb[c + 2]);
  ov[3] = f2bf((r.w - mean) * rstd * g[c + 3] + bb[c + 3]);
  *(u16x4*)&out[(size_t)row * D_ + c] = ov;
}

// ---------------- embedding + ln1(layer0) ----------------
__global__ __launch_bounds__(256) void embed_ln_kernel(const int* __restrict__ idx,
                                                       const float* __restrict__ tk,
                                                       const float* __restrict__ pe,
                                                       const float* __restrict__ g,
                                                       const float* __restrict__ bb,
                                                       float* __restrict__ x,
                                                       unsigned short* __restrict__ out) {
  __shared__ float red[8];
  const int row = blockIdx.x, tid = threadIdx.x;
  const int t = row & (T_ - 1);
  const int id = idx[row];
  const int c = tid * 4;
  float4 a = *(const float4*)&tk[(size_t)id * D_ + c];
  const float4 p = *(const float4*)&pe[(size_t)t * D_ + c];
  a.x += p.x; a.y += p.y; a.z += p.z; a.w += p.w;
  *(float4*)&x[(size_t)row * D_ + c] = a;
  ln_row_store(a, g, bb, row, tid, red, out);
}

// ---------------- LayerNorm fp32 -> bf16 ----------------
__global__ __launch_bounds__(256) void ln_kernel(const float* __restrict__ x,
                                                 const float* __restrict__ g,
                                                 const float* __restrict__ bb,
                                                 unsigned short* __restrict__ out) {
  __shared__ float red[8];
  const int row = blockIdx.x, tid = threadIdx.x;
  const float4 v = *(const float4*)&x[(size_t)row * D_ + tid * 4];
  ln_row_store(v, g, bb, row, tid, red, out);
}

// ---------------- split-K reduce (bf16 partials) + residual + next-LN fused ----------------
__global__ __launch_bounds__(256) void redk_ln_kernel(const unsigned short* __restrict__ part,
                                                      const float* __restrict__ bias,
                                                      float* __restrict__ x,
                                                      const float* __restrict__ g,
                                                      const float* __restrict__ bb,
                                                      unsigned short* __restrict__ out) {
  __shared__ float red[8];
  const int row = blockIdx.x, tid = threadIdx.x;
  const size_t i = (size_t)row * D_ + tid * 4;
  float4 r = *(const float4*)&x[i];
  const float4 bv = *(const float4*)&bias[tid * 4];
  const size_t stride = (size_t)M_ * D_;
  const u16x4 q0 = *(const u16x4*)&part[i];
  const u16x4 q1 = *(const u16x4*)&part[i + stride];
  const u16x4 q2 = *(const u16x4*)&part[i + 2 * stride];
  const u16x4 q3 = *(const u16x4*)&part[i + 3 * stride];
  r.x += bv.x + ((bf2f(q0[0]) + bf2f(q1[0])) + (bf2f(q2[0]) + bf2f(q3[0])));
  r.y += bv.y + ((bf2f(q0[1]) + bf2f(q1[1])) + (bf2f(q2[1]) + bf2f(q3[1])));
  r.z += bv.z + ((bf2f(q0[2]) + bf2f(q1[2])) + (bf2f(q2[2]) + bf2f(q3[2])));
  r.w += bv.w + ((bf2f(q0[3]) + bf2f(q1[3])) + (bf2f(q2[3]) + bf2f(q3[3])));
  *(float4*)&x[i] = r;
  ln_row_store(r, g, bb, row, tid, red, out);
}

// ---------------- merged generic transpose: 4 segments, flat 1D grid ----------------
// Vectorized: float4 global reads (16B/lane), u16x4 global writes (8B/lane).
// LDS tile[64][65] f32, scalar element traffic both phases (stride-65 bank math: 2-way, free).
struct TpSeg {
  const float* in;
  unsigned short* out;
  int R, C;
  long in_bs, out_bs;
  int gx, gy, nblk;
};
struct TpArgs { TpSeg seg[4]; };

__global__ __launch_bounds__(256) void tpose4_kernel(TpArgs a) {
  __shared__ float tile[64][65];
  int id = blockIdx.x;
  int s = 0;
  while (s < 3 && id >= a.seg[s].nblk) { id -= a.seg[s].nblk; s++; }
  const TpSeg g = a.seg[s];
  const int bz = id / (g.gx * g.gy);
  const int rem = id % (g.gx * g.gy);
  const int by = rem / g.gx, bx = rem % g.gx;
  const float* in = g.in + (long)bz * g.in_bs;
  unsigned short* out = g.out + (long)bz * g.out_bs;
  const int t = threadIdx.x;
  const int rb = by * 64, cb = bx * 64;
  const int q16 = t & 15, h16 = t >> 4;
  // read: 64 rows x 64 cols, float4 per thread per iter
#pragma unroll
  for (int i = 0; i < 4; i++) {
    const int row = h16 + i * 16;
    const f32x4 v = *(const f32x4*)&in[(long)(rb + row) * g.C + cb + q16 * 4];
#pragma unroll
    for (int j = 0; j < 4; j++) tile[row][q16 * 4 + j] = v[j];
  }
  __syncthreads();
  // write: out[(cb+ic)*R + rb+ir], u16x4 over ir = q16*4..+3 per output row ic
#pragma unroll
  for (int i = 0; i < 4; i++) {
    const int ic = h16 + i * 16;
    u16x4 o;
#pragma unroll
    for (int k = 0; k < 4; k++) o[k] = f2bf(tile[q16 * 4 + k][ic]);
    *(u16x4*)&out[(long)(cb + ic) * g.R + rb + q16 * 4] = o;
  }
}

// ---------------- merged Wq/Wk/Wv transpose + bias concat (z>=576) ----------------
__global__ __launch_bounds__(256) void qkv_tpose_kernel(const float* __restrict__ Wq,
                                                        const float* __restrict__ Wk,
                                                        const float* __restrict__ Wv,
                                                        const float* __restrict__ bq,
                                                        const float* __restrict__ bk,
                                                        const float* __restrict__ bv,
                                                        unsigned short* __restrict__ out,
                                                        float* __restrict__ bqkv) {
  __shared__ float tile[64][65];
  const int z = blockIdx.z;
  if (z >= 576) {  // bias concat: 12 layers
    if (blockIdx.y != 0) return;
    const int l = z - 576;
    const int tid = threadIdx.y * 64 + threadIdx.x;
    for (int i = tid; i < 1024; i += 256) {
      bqkv[l * 3072 + i] = bq[l * 1024 + i];
      bqkv[l * 3072 + 1024 + i] = bk[l * 1024 + i];
      bqkv[l * 3072 + 2048 + i] = bv[l * 1024 + i];
    }
    return;
  }
  const int seg = z / 192, zz = z % 192;
  const float* in = (seg == 0 ? Wq : seg == 1 ? Wk : Wv) + (long)zz * 65536;
  unsigned short* o = out + (long)seg * 1048576 + (long)(zz & 15) * 65536 + (long)(zz >> 4) * 3145728;
  const int tx = threadIdx.x, ty = threadIdx.y;
  const int r0 = blockIdx.y * 64;
#pragma unroll
  for (int i = 0; i < 16; i++) tile[ty + i * 4][tx] = in[(long)(r0 + ty + i * 4) * 64 + tx];
  __syncthreads();
  const int oc = blockIdx.y * 64 + tx;
#pragma unroll
  for (int i = 0; i < 16; i++)
    o[(long)(ty + i * 4) * 1024 + oc] = f2bf(tile[tx][ty + i * 4]);
}

// ================ 256x256 8-phase GEMM (m201-style) ================
// EPI: 0 bf16 +bias ; 1 bf16 gelu ; 3 f32 +bias ; 5 bf16 PARTIAL (no bias) at z*M*N
template <int EPI>
__global__ __launch_bounds__(512, 2) void gemm256(const unsigned short* __restrict__ A,
                                                  const unsigned short* __restrict__ Bt,
                                                  const float* __restrict__ bias,
                                                  void* outp, int Kc, int ld, int N) {
  __shared__ unsigned short lds[65536];
  const int tid = threadIdx.x;
  const int lane = tid & 63, w = tid >> 6;
  const int wm = w >> 2, wn = w & 3;
  const int l15 = lane & 15, lh = lane >> 4;
  int bx = blockIdx.x, by = blockIdx.y;
  xcd_swz(bx, by);
  const int row0 = by * 256, col0 = bx * 256;
  const int z = blockIdx.z;
  const int nt = Kc >> 6;
  const int laneoff = (lh * 8) ^ (((l15 >> 1) & 3) << 3);
  const int cswz = ((tid & 3) * 8) ^ (((tid >> 3) & 3) << 3);
  const unsigned short* gA = A + (size_t)(row0 + (tid >> 2)) * ld + z * Kc + cswz;
  const unsigned short* gB = Bt + (size_t)(col0 + (tid >> 2)) * ld + z * Kc + cswz;
  const size_t rblk = (size_t)128 * ld;
  const int arow = wm * 128 + l15;
  const int brow = wn * 64 + l15;

  f32x4 acc[8][4];
#pragma unroll
  for (int m = 0; m < 8; m++)
#pragma unroll
    for (int n = 0; n < 4; n++) acc[m][n] = f32x4{0.f, 0.f, 0.f, 0.f};

  auto issueA = [&](int t, int r) {
    unsigned short* d = lds + (t & 1) * 32768 + r * 8192 + tid * 8;
    const unsigned short* s = gA + t * 64 + r * 32;
    GL2LDS(s, d);
    GL2LDS(s + rblk, d + 4096);
  };
  auto issueB = [&](int t, int r) {
    unsigned short* d = lds + (t & 1) * 32768 + 16384 + r * 8192 + tid * 8;
    const unsigned short* s = gB + t * 64 + r * 32;
    GL2LDS(s, d);
    GL2LDS(s + rblk, d + 4096);
  };

  issueA(0, 0); issueB(0, 0); issueA(0, 1); issueB(0, 1);
  issueA(1, 0); issueB(1, 0);
  WVM(8);
  BARRIER();

  bf16x8 aF[4], bF[4];
  for (int t = 0; t < nt; ++t) {
    const bool last = (t == nt - 1);
    const unsigned short* ab = lds + (t & 1) * 32768;
    const unsigned short* bb2 = ab + 16384;
    // ---- P1 ----
#pragma unroll
    for (int m = 0; m < 4; m++) aF[m] = *(const bf16x8*)(ab + (arow + m * 16) * 32 + laneoff);
#pragma unroll
    for (int n = 0; n < 4; n++) bF[n] = *(const bf16x8*)(bb2 + (brow + n * 16) * 32 + laneoff);
    if (!last) issueA(t + 1, 1);
    BARRIER();
    __builtin_amdgcn_s_setprio(1);
#pragma unroll
    for (int m = 0; m < 4; m++)
#pragma unroll
      for (int n = 0; n < 4; n++) acc[m][n] = MFMA16(aF[m], bF[n], acc[m][n]);
    __builtin_amdgcn_s_setprio(0);
    BARRIER();
    // ---- P2 ----
#pragma unroll
    for (int m = 0; m < 4; m++) aF[m] = *(const bf16x8*)(ab + (arow + (m + 4) * 16) * 32 + laneoff);
    if (!last) issueB(t + 1, 1);
    BARRIER();
    __builtin_amdgcn_s_setprio(1);
#pragma unroll
    for (int m = 0; m < 4; m++)
#pragma unroll
      for (int n = 0; n < 4; n++) acc[m + 4][n] = MFMA16(aF[m], bF[n], acc[m + 4][n]);
    __builtin_amdgcn_s_setprio(0);
    if (last) { WVM(0); } else { WVM(8); }
    BARRIER();
    // ---- P3 ----
#pragma unroll
    for (int m = 0; m < 4; m++) aF[m] = *(const bf16x8*)(ab + 8192 + (arow + m * 16) * 32 + laneoff);
#pragma unroll
    for (int n = 0; n < 4; n++) bF[n] = *(const bf16x8*)(bb2 + 8192 + (brow + n * 16) * 32 + laneoff);
    if (t + 2 < nt) issueA(t + 2, 0);
    BARRIER();
    __builtin_amdgcn_s_setprio(1);
#pragma unroll
    for (int m = 0; m < 4; m++)
#pragma unroll
      for (int n = 0; n < 4; n++) acc[m][n] = MFMA16(aF[m], bF[n], acc[m][n]);
    __builtin_amdgcn_s_setprio(0);
    BARRIER();
    // ---- P4 ----
#pragma unroll
    for (int m = 0; m < 4; m++) aF[m] = *(const bf16x8*)(ab + 8192 + (arow + (m + 4) * 16) * 32 + laneoff);
    if (t + 2 < nt) issueB(t + 2, 0);
    BARRIER();
    __builtin_amdgcn_s_setprio(1);
#pragma unroll
    for (int m = 0; m < 4; m++)
#pragma unroll
      for (int n = 0; n < 4; n++) acc[m + 4][n] = MFMA16(aF[m], bF[n], acc[m + 4][n]);
    __builtin_amdgcn_s_setprio(0);
    if (!last) {
      if (t == nt - 2) { WVM(4); } else { WVM(8); }
    }
    BARRIER();
  }

#pragma unroll
  for (int n = 0; n < 4; n++) {
    const int c = col0 + wn * 64 + n * 16 + l15;
    const float bv = (EPI == 5) ? 0.f : bias[c];
#pragma unroll
    for (int m = 0; m < 8; m++) {
      const int r = row0 + wm * 128 + m * 16 + lh * 4;
#pragma unroll
      for (int j = 0; j < 4; j++) {
        float val = acc[m][n][j] + bv;
        const size_t oi = (size_t)(r + j) * N + c;
        if constexpr (EPI == 0) {
          ((unsigned short*)outp)[oi] = f2bf(val);
        } else if constexpr (EPI == 1) {
          val = 0.5f * val * (1.f + erff(val * 0.70710678118654752f));
          ((unsigned short*)outp)[oi] = f2bf(val);
        } else if constexpr (EPI == 5) {
          ((unsigned short*)outp)[(size_t)z * ((size_t)gridDim.y * 256) * N + oi] = f2bf(val);
        } else {
          ((float*)outp)[oi] = val;
        }
      }
    }
  }
}

// ---------------- pipelined 128xBN GEMM (m97-style, counted vmcnt) ----------------
template <int EPI, int BN, int DEPTH>
__global__ __launch_bounds__(256) void gemmP(const unsigned short* __restrict__ A,
                                             const unsigned short* __restrict__ Bt,
                                             const float* __restrict__ bias,
                                             const float* resid, void* outp,
                                             int K, int N) {
  constexpr int NB = DEPTH + 1;
  constexpr int TILE = (128 + BN) * 32;
  constexpr int NF = BN / 32;
  __shared__ unsigned short lds[NB * TILE];
  const int tid = threadIdx.x;
  const int lane = tid & 63;
  const int w = tid >> 6;
  const int l15 = lane & 15, lh = lane >> 4;
  const int wr = (w >> 1) * 64, wc = (w & 1) * (BN / 2);
  int bx = blockIdx.x, by = blockIdx.y;
  xcd_swz(bx, by);
  const int row0 = by * 128, col0 = bx * BN;

  const unsigned short* gA = A + (size_t)(row0 + (tid >> 2)) * K + (tid & 3) * 8;
  const unsigned short* gB = Bt + (size_t)(col0 + (tid >> 2)) * K + (tid & 3) * 8;
  const size_t rstep = (size_t)64 * K;

  f32x4 acc[4][NF];
#pragma unroll
  for (int m = 0; m < 4; m++)
#pragma unroll
    for (int n = 0; n < NF; n++) acc[m][n] = f32x4{0.f, 0.f, 0.f, 0.f};

  const int nt = K >> 5;

  auto ISSUE = [&](int t) {
    unsigned short* buf = lds + (t % NB) * TILE;
    const unsigned short* a = gA + t * 32;
    GL2LDS(a, buf + tid * 8);
    GL2LDS(a + rstep, buf + 2048 + tid * 8);
    const unsigned short* b = gB + t * 32;
    unsigned short* bb = buf + 128 * 32;
    GL2LDS(b, bb + tid * 8);
    if constexpr (BN == 128) GL2LDS(b + rstep, bb + 2048 + tid * 8);
  };

#pragma unroll
  for (int t = 0; t < DEPTH; t++) ISSUE(t);

  for (int i = 0; i < nt; i++) {
    const int rem = nt - 1 - i;
    if (rem >= DEPTH - 1) {
      if constexpr ((2 + (BN == 128 ? 2 : 1)) * (DEPTH - 1) == 4) WVM(4);
      else WVM(6);
    } else if (DEPTH == 3 && rem == 1) {
      WVM(3);
    } else {
      WVM(0);
    }
    BARRIER();
    const unsigned short* buf = lds + (i % NB) * TILE;
    const unsigned short* rdA = buf + (wr + l15) * 32 + lh * 8;
    const unsigned short* rdB = buf + 128 * 32 + (wc + l15) * 32 + lh * 8;
    bf16x8 aF[4], bF[NF];
#pragma unroll
    for (int m = 0; m < 4; m++) aF[m] = *(const bf16x8*)(rdA + m * 512);
#pragma unroll
    for (int n = 0; n < NF; n++) bF[n] = *(const bf16x8*)(rdB + n * 512);
#pragma unroll
    for (int m = 0; m < 4; m++)
#pragma unroll
      for (int n = 0; n < NF; n++) acc[m][n] = MFMA16(aF[m], bF[n], acc[m][n]);
    if (i + DEPTH < nt) ISSUE(i + DEPTH);
  }

#pragma unroll
  for (int n = 0; n < NF; n++) {
    const int c = col0 + wc + n * 16 + l15;
    const float bv = bias[c];
#pragma unroll
    for (int m = 0; m < 4; m++) {
      const int r = row0 + wr + m * 16 + lh * 4;
#pragma unroll
      for (int j = 0; j < 4; j++) {
        float val = acc[m][n][j] + bv;
        const size_t oi = (size_t)(r + j) * N + c;
        if constexpr (EPI == 0) {
          ((unsigned short*)outp)[oi] = f2bf(val);
        } else if constexpr (EPI == 1) {
          val = 0.5f * val * (1.f + erff(val * 0.70710678118654752f));
          ((unsigned short*)outp)[oi] = f2bf(val);
        } else if constexpr (EPI == 2) {
          ((float*)outp)[oi] = resid[oi] + val;
        } else {
          ((float*)outp)[oi] = val;
        }
      }
    }
  }
}

// ---------------- causal flash attention: QBLK=128, 8 waves, swapped QK^T ----------------
__global__ __launch_bounds__(512) void attn_kernel(const unsigned short* __restrict__ qkv,
                                                   unsigned short* __restrict__ o) {
  __shared__ unsigned short Ks[2][64 * 72];
  __shared__ unsigned short Vts[2][64 * 72];
  __shared__ unsigned short Ps[8][16 * 72];
  const int tid = threadIdx.x;
  const int lane = tid & 63, w = tid >> 6;
  const int l15 = lane & 15, lh = lane >> 4;
  const int qt = gridDim.x - 1 - blockIdx.x;
  const int bh = blockIdx.y;
  const int b = bh >> 4, h = bh & 15;
  const int rb = b * T_;
  const int q0 = qt * 128;
  const int nkt = 2 * qt + 2;

  bf16x8 qf[2];
  {
    const unsigned short* qp = qkv + (size_t)(rb + q0 + w * 16 + l15) * 3072 + h * 64 + lh * 8;
    qf[0] = *(const bf16x8*)qp;
    qf[1] = *(const bf16x8*)(qp + 32);
#pragma unroll
    for (int e = 0; e < 2; e++) {
      u16x8 u = __builtin_bit_cast(u16x8, qf[e]);
#pragma unroll
      for (int j = 0; j < 8; j++) u[j] = f2bf(bf2f(u[j]) * 0.1803368801111832f);
      qf[e] = __builtin_bit_cast(bf16x8, u);
    }
  }
  f32x4 oa[4];
  float mrun = -1e30f, lrun = 0.f;
#pragma unroll
  for (int n = 0; n < 4; n++) oa[n] = f32x4{0.f, 0.f, 0.f, 0.f};

  const int qrow = q0 + w * 16 + l15;

  u16x8 kreg, vreg;
  auto loadKV = [&](int kt) {
    kreg = *(const u16x8*)(qkv + (size_t)(rb + kt * 64 + (tid >> 3)) * 3072 + 1024 + h * 64 +
                           (tid & 7) * 8);
    vreg = *(const u16x8*)(qkv + (size_t)(rb + kt * 64 + lane) * 3072 + 2048 + h * 64 + w * 8);
  };
  auto writeKV = [&](int kt) {
    const int bs = kt & 1;
    *(u16x8*)&Ks[bs][(tid >> 3) * 72 + (tid & 7) * 8] = kreg;
#pragma unroll
    for (int j = 0; j < 8; j++) Vts[bs][(w * 8 + j) * 72 + lane] = vreg[j];
  };

  loadKV(0);
  WVM(0);
  writeKV(0);
  loadKV(1);
  WLG();
  BARRIER();

  for (int kt = 0; kt < nkt; ++kt) {
    const int bs = kt & 1;
    f32x4 sa[4];
#pragma unroll
    for (int n = 0; n < 4; n++) sa[n] = f32x4{0.f, 0.f, 0.f, 0.f};
    __builtin_amdgcn_s_setprio(1);
#pragma unroll
    for (int ke = 0; ke < 2; ke++) {
#pragma unroll
      for (int n = 0; n < 4; n++) {
        const bf16x8 kf = *(const bf16x8*)&Ks[bs][(n * 16 + l15) * 72 + ke * 32 + lh * 8];
        sa[n] = MFMA16(kf, qf[ke], sa[n]);
      }
    }
    __builtin_amdgcn_s_setprio(0);
    float sv[4][4];
    const bool diag = (kt >= 2 * qt);
#pragma unroll
    for (int n = 0; n < 4; n++)
#pragma unroll
      for (int j = 0; j < 4; j++) {
        float v = sa[n][j];
        if (diag && (kt * 64 + n * 16 + lh * 4 + j) > qrow) v = -1e30f;
        sv[n][j] = v;
      }
    float mx = sv[0][0];
#pragma unroll
    for (int n = 0; n < 4; n++)
#pragma unroll
      for (int j = 0; j < 4; j++) mx = fmaxf(mx, sv[n][j]);
    mx = fmaxf(mx, __shfl_xor(mx, 16));
    mx = fmaxf(mx, __shfl_xor(mx, 32));
    const bool small = (mx - mrun <= 8.f);
    if (!__all(small)) {
      const float m2 = fmaxf(mrun, mx);
      const float corr = exp2f(mrun - m2);
      mrun = m2;
      lrun *= corr;
      float cO[4];
#pragma unroll
      for (int j = 0; j < 4; j++) cO[j] = __shfl(corr, lh * 4 + j);
#pragma unroll
      for (int n = 0; n < 4; n++)
#pragma unroll
        for (int j = 0; j < 4; j++) oa[n][j] *= cO[j];
    }
    float rs = 0.f;
#pragma unroll
    for (int n = 0; n < 4; n++) {
      u16x4 pk;
#pragma unroll
      for (int j = 0; j < 4; j++) {
        const float p = exp2f(sv[n][j] - mrun);
        rs += p;
        pk[j] = f2bf(p);
      }
      *(u16x4*)&Ps[w][l15 * 72 + n * 16 + lh * 4] = pk;
    }
    rs += __shfl_xor(rs, 16);
    rs += __shfl_xor(rs, 32);
    lrun += rs;
    __builtin_amdgcn_s_setprio(1);
#pragma unroll
    for (int ks = 0; ks < 2; ks++) {
      const bf16x8 pf = *(const bf16x8*)&Ps[w][l15 * 72 + ks * 32 + lh * 8];
#pragma unroll
      for (int n = 0; n < 4; n++) {
        const bf16x8 vf = *(const bf16x8*)&Vts[bs][(n * 16 + l15) * 72 + ks * 32 + lh * 8];
        oa[n] = MFMA16(pf, vf, oa[n]);
      }
    }
    __builtin_amdgcn_s_setprio(0);
    if (kt + 1 < nkt) {
      WVM(0);
      writeKV(kt + 1);
      if (kt + 2 < nkt) loadKV(kt + 2);
      WLG();
      BARRIER();
    }
  }
  float linv[4];
#pragma unroll
  for (int j = 0; j < 4; j++) linv[j] = 1.f / __shfl(lrun, lh * 4 + j);
#pragma unroll
  for (int n = 0; n < 4; n++)
#pragma unroll
    for (int j = 0; j < 4; j++) {
      o[(size_t)(rb + q0 + w * 16 + lh * 4 + j) * D_ + h * 64 + n * 16 + l15] =
          f2bf(oa[n][j] * linv[j]);
    }
}

// ---------------- host orchestration ----------------
extern "C" void kernel_launch(void* const* d_in, const int* in_sizes, int n_in,
                              void* d_out, int out_size, void* d_ws, size_t ws_size,
                              hipStream_t stream) {
  const int* idx = (const int*)d_in[0];
  const float* tk = (const float*)d_in[1];
  const float* pe = (const float*)d_in[2];
  const float* ln1g = (const float*)d_in[3];
  const float* ln1b = (const float*)d_in[4];
  const float* Wq = (const float*)d_in[5];
  const float* bq = (const float*)d_in[6];
  const float* Wk = (const float*)d_in[7];
  const float* bk = (const float*)d_in[8];
  const float* Wv = (const float*)d_in[9];
  const float* bv = (const float*)d_in[10];
  const float* Wo = (const float*)d_in[11];
  const float* bo = (const float*)d_in[12];
  const float* ln2g = (const float*)d_in[13];
  const float* ln2b = (const float*)d_in[14];
  const float* W1 = (const float*)d_in[15];
  const float* b1 = (const float*)d_in[16];
  const float* W2 = (const float*)d_in[17];
  const float* b2 = (const float*)d_in[18];
  const float* lnfg = (const float*)d_in[19];
  const float* lnfb = (const float*)d_in[20];
  const float* Wout = (const float*)d_in[21];
  const float* bout = (const float*)d_in[22];

  char* ws = (char*)d_ws;
  size_t off = 0;
  auto alloc = [&](size_t bytes) {
    void* p = ws + off;
    off += (bytes + 255) & ~(size_t)255;
    return p;
  };
  unsigned short* wqkv = (unsigned short*)alloc(12ull * 3072 * 1024 * 2);
  unsigned short* wo = (unsigned short*)alloc(12ull * 1024 * 1024 * 2);
  unsigned short* w1 = (unsigned short*)alloc(12ull * 4096 * 1024 * 2);
  unsigned short* w2 = (unsigned short*)alloc(12ull * 4096 * 1024 * 2);
  unsigned short* wout = (unsigned short*)alloc(8192ull * 1024 * 2);
  float* bqkv = (float*)alloc(12ull * 3072 * 4);
  float* x = (float*)alloc(4096ull * 1024 * 4);
  unsigned short* hb = (unsigned short*)alloc(4096ull * 1024 * 2);
  unsigned short* qkvb = (unsigned short*)alloc(4096ull * 3072 * 2);
  unsigned short* ob = (unsigned short*)alloc(4096ull * 1024 * 2);
  unsigned short* ub = (unsigned short*)alloc(4096ull * 4096 * 2);
  unsigned short* part = (unsigned short*)alloc(4ull * 4096 * 1024 * 2);

  const dim3 tb(64, 4);
  TpArgs ta;
  ta.seg[0] = {Wo, wo, 1024, 1024, 1048576, 1048576, 16, 16, 3072};
  ta.seg[1] = {W1, w1, 1024, 4096, 4194304, 4194304, 64, 16, 12288};
  ta.seg[2] = {W2, w2, 4096, 1024, 4194304, 4194304, 16, 64, 12288};
  ta.seg[3] = {Wout, wout, 1024, 8192, 0, 0, 128, 16, 2048};
  tpose4_kernel<<<29696, 256, 0, stream>>>(ta);
  qkv_tpose_kernel<<<dim3(1, 16, 588), tb, 0, stream>>>(Wq, Wk, Wv, bq, bk, bv, wqkv, bqkv);
  embed_ln_kernel<<<4096, 256, 0, stream>>>(idx, tk, pe, ln1g, ln1b, x, hb);

  for (int l = 0; l < 12; l++) {
    gemm256<0><<<dim3(12, 16), 512, 0, stream>>>(hb, wqkv + (size_t)l * 3145728,
                                                 bqkv + l * 3072, qkvb, 1024, 1024, 3072);
    attn_kernel<<<dim3(8, 64), 512, 0, stream>>>(qkvb, ob);
    gemmP<2, 64, 3><<<dim3(16, 32), 256, 0, stream>>>(ob, wo + (size_t)l * 1048576,
                                                      bo + l * 1024, x, x, 1024, 1024);
    ln_kernel<<<4096, 256, 0, stream>>>(x, ln2g + l * 1024, ln2b + l * 1024, hb);
    gemm256<1><<<dim3(16, 16), 512, 0, stream>>>(hb, w1 + (size_t)l * 4194304,
                                                 b1 + l * 4096, ub, 1024, 1024, 4096);
    gemm256<5><<<dim3(4, 16, 4), 512, 0, stream>>>(ub, w2 + (size_t)l * 4194304,
                                                   nullptr, part, 1024, 4096, 1024);
    const float* ng = (l < 11) ? (ln1g + (l + 1) * 1024) : lnfg;
    const float* nb = (l < 11) ? (ln1b + (l + 1) * 1024) : lnfb;
    redk_ln_kernel<<<4096, 256, 0, stream>>>(part, b2 + l * 1024, x, ng, nb, hb);
  }
  gemmP<3, 128, 2><<<dim3(64, 32), 256, 0, stream>>>(hb, wout, bout, nullptr, d_out, 1024, 8192);
}

// Round 12
// 2943.952 us; speedup vs baseline: 1.0029x; 1.0029x over previous
//
#include <hip/hip_runtime.h>

#define B_ 4
#define T_ 1024
#define D_ 1024
#define H_ 16
#define DH_ 64
#define L_ 12
#define FF_ 4096
#define V_ 8192
#define M_ 4096  // B*T

typedef short bf16x8 __attribute__((ext_vector_type(8)));
typedef unsigned short u16x8 __attribute__((ext_vector_type(8)));
typedef unsigned short u16x4 __attribute__((ext_vector_type(4)));
typedef float f32x4 __attribute__((ext_vector_type(4)));

typedef const __attribute__((address_space(1))) void* gas1;
typedef __attribute__((address_space(3))) void* las3;
#define GL2LDS(g, l) __builtin_amdgcn_global_load_lds((gas1)(g), (las3)(l), 16, 0, 0)
#define MFMA16(a, b, c) __builtin_amdgcn_mfma_f32_16x16x32_bf16((a), (b), (c), 0, 0, 0)
#define WVM(n) asm volatile("s_waitcnt vmcnt(" #n ")" ::: "memory")
#define WLG() asm volatile("s_waitcnt lgkmcnt(0)" ::: "memory")
#define BARRIER() asm volatile("s_barrier" ::: "memory")

static __device__ __forceinline__ unsigned short f2bf(float f) {
  unsigned int u = __builtin_bit_cast(unsigned int, f);
  u += 0x7fffu + ((u >> 16) & 1u);
  return (unsigned short)(u >> 16);
}
static __device__ __forceinline__ float bf2f(unsigned short u) {
  unsigned int v = (unsigned int)u << 16;
  return __builtin_bit_cast(float, v);
}

// T1: bijective XCD swizzle (all grids have gx*gy % 8 == 0)
static __device__ __forceinline__ void xcd_swz(int& bx, int& by) {
  const int gx = gridDim.x;
  const int id = by * gx + bx;
  const int q = (gx * gridDim.y) >> 3;
  const int nid = (id & 7) * q + (id >> 3);
  bx = nid % gx;
  by = nid / gx;
}

// row-LN of an in-register row chunk (4 floats/thread, 256 thr), then bf16 store
static __device__ __forceinline__ void ln_row_store(float4 r, const float* __restrict__ g,
                                                    const float* __restrict__ bb, int row,
                                                    int tid, float* red,
                                                    unsigned short* __restrict__ out) {
  float s = r.x + r.y + r.z + r.w;
  float s2 = r.x * r.x + r.y * r.y + r.z * r.z + r.w * r.w;
#pragma unroll
  for (int off = 32; off; off >>= 1) {
    s += __shfl_down(s, off);
    s2 += __shfl_down(s2, off);
  }
  if ((tid & 63) == 0) { red[tid >> 6] = s; red[4 + (tid >> 6)] = s2; }
  __syncthreads();
  const float ts = red[0] + red[1] + red[2] + red[3];
  const float ts2 = red[4] + red[5] + red[6] + red[7];
  const float mean = ts * (1.f / 1024.f);
  const float var = ts2 * (1.f / 1024.f) - mean * mean;
  const float rstd = rsqrtf(var + 1e-5f);
  const int c = tid * 4;
  u16x4 ov;
  ov[0] = f2bf((r.x - mean) * rstd * g[c] + bb[c]);
  ov[1] = f2bf((r.y - mean) * rstd * g[c + 1] + bb[c + 1]);
  ov[2] = f2bf((r.z - mean) * rstd * g[c + 2] + bb[c + 2]);
  ov[3] = f2bf((r.w - mean) * rstd * g[c + 3] + bb[c + 3]);
  *(u16x4*)&out[(size_t)row * D_ + c] = ov;
}

// ---------------- embedding + ln1(layer0) ----------------
__global__ __launch_bounds__(256) void embed_ln_kernel(const int* __restrict__ idx,
                                                       const float* __restrict__ tk,
                                                       const float* __restrict__ pe,
                                                       const float* __restrict__ g,
                                                       const float* __restrict__ bb,
                                                       float* __restrict__ x,
                                                       unsigned short* __restrict__ out) {
  __shared__ float red[8];
  const int row = blockIdx.x, tid = threadIdx.x;
  const int t = row & (T_ - 1);
  const int id = idx[row];
  const int c = tid * 4;
  float4 a = *(const float4*)&tk[(size_t)id * D_ + c];
  const float4 p = *(const float4*)&pe[(size_t)t * D_ + c];
  a.x += p.x; a.y += p.y; a.z += p.z; a.w += p.w;
  *(float4*)&x[(size_t)row * D_ + c] = a;
  ln_row_store(a, g, bb, row, tid, red, out);
}

// ---------------- LayerNorm fp32 -> bf16 ----------------
__global__ __launch_bounds__(256) void ln_kernel(const float* __restrict__ x,
                                                 const float* __restrict__ g,
                                                 const float* __restrict__ bb,
                                                 unsigned short* __restrict__ out) {
  __shared__ float red[8];
  const int row = blockIdx.x, tid = threadIdx.x;
  const float4 v = *(const float4*)&x[(size_t)row * D_ + tid * 4];
  ln_row_store(v, g, bb, row, tid, red, out);
}

// ---------------- split-K reduce (bf16 partials) + residual + next-LN fused ----------------
__global__ __launch_bounds__(256) void redk_ln_kernel(const unsigned short* __restrict__ part,
                                                      const float* __restrict__ bias,
                                                      float* __restrict__ x,
                                                      const float* __restrict__ g,
                                                      const float* __restrict__ bb,
                                                      unsigned short* __restrict__ out) {
  __shared__ float red[8];
  const int row = blockIdx.x, tid = threadIdx.x;
  const size_t i = (size_t)row * D_ + tid * 4;
  float4 r = *(const float4*)&x[i];
  const float4 bv = *(const float4*)&bias[tid * 4];
  const size_t stride = (size_t)M_ * D_;
  const u16x4 q0 = *(const u16x4*)&part[i];
  const u16x4 q1 = *(const u16x4*)&part[i + stride];
  const u16x4 q2 = *(const u16x4*)&part[i + 2 * stride];
  const u16x4 q3 = *(const u16x4*)&part[i + 3 * stride];
  r.x += bv.x + ((bf2f(q0[0]) + bf2f(q1[0])) + (bf2f(q2[0]) + bf2f(q3[0])));
  r.y += bv.y + ((bf2f(q0[1]) + bf2f(q1[1])) + (bf2f(q2[1]) + bf2f(q3[1])));
  r.z += bv.z + ((bf2f(q0[2]) + bf2f(q1[2])) + (bf2f(q2[2]) + bf2f(q3[2])));
  r.w += bv.w + ((bf2f(q0[3]) + bf2f(q1[3])) + (bf2f(q2[3]) + bf2f(q3[3])));
  *(float4*)&x[i] = r;
  ln_row_store(r, g, bb, row, tid, red, out);
}

// ---------------- merged generic transpose: 4 segments, 128x128 tiles, bf16 LDS ----------------
// Read: float4 (512B/row bursts), cvt to bf16, store to LDS with slot-XOR (slot = c4 ^ (row>>3)).
// Write: gather 8 rows per u16x8, 256B/row bursts, 1KB/wave-instruction. Gather banks: 2-way (free):
// bank = (2*((4i^seg)&15) + (od>>1)) mod 32 covers all 32 banks x2 lanes.
struct TpSeg {
  const float* in;
  unsigned short* out;
  int R, C;
  long in_bs, out_bs;
  int gx, gy, nblk;
};
struct TpArgs { TpSeg seg[4]; };

__global__ __launch_bounds__(256) void tpose4_kernel(TpArgs a) {
  __shared__ unsigned short tile[128 * 128];  // 32 KB
  int id = blockIdx.x;
  int s = 0;
  while (s < 3 && id >= a.seg[s].nblk) { id -= a.seg[s].nblk; s++; }
  const TpSeg g = a.seg[s];
  const int bz = id / (g.gx * g.gy);
  const int rem = id % (g.gx * g.gy);
  const int by = rem / g.gx, bx = rem % g.gx;
  const float* in = g.in + (long)bz * g.in_bs;
  unsigned short* out = g.out + (long)bz * g.out_bs;
  const int t = threadIdx.x;
  const int rb = by * 128, cb = bx * 128;
  {
    const int c4 = t & 31, rt = t >> 5;  // 32 float4/row, 8 rows/pass
#pragma unroll
    for (int i = 0; i < 16; i++) {
      const int row = rt + i * 8;  // row>>3 == i (wave-constant)
      const f32x4 v = *(const f32x4*)&in[(long)(rb + row) * g.C + cb + c4 * 4];
      u16x4 b;
#pragma unroll
      for (int j = 0; j < 4; j++) b[j] = f2bf(v[j]);
      *(u16x4*)&tile[row * 128 + ((c4 ^ (row >> 3)) * 4)] = b;
    }
  }
  __syncthreads();
  {
    const int seg = t & 15, od = t >> 4;  // 16 u16x8/out-row, 4 rows/wave-instr
#pragma unroll
    for (int i = 0; i < 8; i++) {
      const int oc = od + i * 16;
      const int slot = (oc >> 2) ^ seg;  // r>>3 == seg for r = seg*8+k
      u16x8 o;
#pragma unroll
      for (int k = 0; k < 8; k++) o[k] = tile[(seg * 8 + k) * 128 + slot * 4 + (oc & 3)];
      *(u16x8*)&out[(long)(cb + oc) * g.R + rb + seg * 8] = o;
    }
  }
}

// ---------------- merged Wq/Wk/Wv transpose (256x64 tiles) + bias concat ----------------
// blk 0..2303: transpose block (zq = blk>>2, ry = blk&3); blk 2304..2315: bias concat.
__global__ __launch_bounds__(256) void qkv_tpose_kernel(const float* __restrict__ Wq,
                                                        const float* __restrict__ Wk,
                                                        const float* __restrict__ Wv,
                                                        const float* __restrict__ bq,
                                                        const float* __restrict__ bk,
                                                        const float* __restrict__ bv,
                                                        unsigned short* __restrict__ out,
                                                        float* __restrict__ bqkv) {
  __shared__ unsigned short tile[256 * 64];  // 32 KB
  const int blk = blockIdx.x;
  const int tid = threadIdx.x;
  if (blk >= 2304) {
    const int l = blk - 2304;
    for (int i = tid; i < 1024; i += 256) {
      bqkv[l * 3072 + i] = bq[l * 1024 + i];
      bqkv[l * 3072 + 1024 + i] = bk[l * 1024 + i];
      bqkv[l * 3072 + 2048 + i] = bv[l * 1024 + i];
    }
    return;
  }
  const int zq = blk >> 2, ry = blk & 3;
  const int seg = zq / 192, zz = zq % 192;
  const float* in = (seg == 0 ? Wq : seg == 1 ? Wk : Wv) + (long)zz * 65536;
  unsigned short* o =
      out + (long)seg * 1048576 + (long)(zz & 15) * 65536 + (long)(zz >> 4) * 3145728;
  const int rb = ry * 256;
  {
    const int c4 = tid & 15, rt = tid >> 4;  // 16 float4/row (full 64-col row), 16 rows/pass
#pragma unroll
    for (int i = 0; i < 16; i++) {
      const int row = rt + i * 16;  // row>>4 == i (wave-constant)
      const f32x4 v = *(const f32x4*)&in[(long)(rb + row) * 64 + c4 * 4];
      u16x4 b;
#pragma unroll
      for (int j = 0; j < 4; j++) b[j] = f2bf(v[j]);
      *(u16x4*)&tile[row * 64 + ((c4 ^ ((row >> 4) & 15)) * 4)] = b;
    }
  }
  __syncthreads();
  {
    const int l32 = tid & 31, od = tid >> 5;  // 32 u16x8/out-row, 2 rows/wave-instr
#pragma unroll
    for (int i = 0; i < 8; i++) {
      const int oc = od + i * 8;
      const int x = l32 >> 1;  // (r>>4)&15 for r = l32*8+k
      const int slot = (oc >> 2) ^ x;
      u16x8 v;
#pragma unroll
      for (int k = 0; k < 8; k++) v[k] = tile[(l32 * 8 + k) * 64 + slot * 4 + (oc & 3)];
      *(u16x8*)&o[(long)oc * 1024 + rb + l32 * 8] = v;
    }
  }
}

// ================ 256x256 8-phase GEMM (m201-style) ================
// EPI: 0 bf16 +bias ; 1 bf16 gelu ; 3 f32 +bias ; 5 bf16 PARTIAL (no bias) at z*M*N
template <int EPI>
__global__ __launch_bounds__(512, 2) void gemm256(const unsigned short* __restrict__ A,
                                                  const unsigned short* __restrict__ Bt,
                                                  const float* __restrict__ bias,
                                                  void* outp, int Kc, int ld, int N) {
  __shared__ unsigned short lds[65536];
  const int tid = threadIdx.x;
  const int lane = tid & 63, w = tid >> 6;
  const int wm = w >> 2, wn = w & 3;
  const int l15 = lane & 15, lh = lane >> 4;
  int bx = blockIdx.x, by = blockIdx.y;
  xcd_swz(bx, by);
  const int row0 = by * 256, col0 = bx * 256;
  const int z = blockIdx.z;
  const int nt = Kc >> 6;
  const int laneoff = (lh * 8) ^ (((l15 >> 1) & 3) << 3);
  const int cswz = ((tid & 3) * 8) ^ (((tid >> 3) & 3) << 3);
  const unsigned short* gA = A + (size_t)(row0 + (tid >> 2)) * ld + z * Kc + cswz;
  const unsigned short* gB = Bt + (size_t)(col0 + (tid >> 2)) * ld + z * Kc + cswz;
  const size_t rblk = (size_t)128 * ld;
  const int arow = wm * 128 + l15;
  const int brow = wn * 64 + l15;

  f32x4 acc[8][4];
#pragma unroll
  for (int m = 0; m < 8; m++)
#pragma unroll
    for (int n = 0; n < 4; n++) acc[m][n] = f32x4{0.f, 0.f, 0.f, 0.f};

  auto issueA = [&](int t, int r) {
    unsigned short* d = lds + (t & 1) * 32768 + r * 8192 + tid * 8;
    const unsigned short* s = gA + t * 64 + r * 32;
    GL2LDS(s, d);
    GL2LDS(s + rblk, d + 4096);
  };
  auto issueB = [&](int t, int r) {
    unsigned short* d = lds + (t & 1) * 32768 + 16384 + r * 8192 + tid * 8;
    const unsigned short* s = gB + t * 64 + r * 32;
    GL2LDS(s, d);
    GL2LDS(s + rblk, d + 4096);
  };

  issueA(0, 0); issueB(0, 0); issueA(0, 1); issueB(0, 1);
  issueA(1, 0); issueB(1, 0);
  WVM(8);
  BARRIER();

  bf16x8 aF[4], bF[4];
  for (int t = 0; t < nt; ++t) {
    const bool last = (t == nt - 1);
    const unsigned short* ab = lds + (t & 1) * 32768;
    const unsigned short* bb2 = ab + 16384;
    // ---- P1 ----
#pragma unroll
    for (int m = 0; m < 4; m++) aF[m] = *(const bf16x8*)(ab + (arow + m * 16) * 32 + laneoff);
#pragma unroll
    for (int n = 0; n < 4; n++) bF[n] = *(const bf16x8*)(bb2 + (brow + n * 16) * 32 + laneoff);
    if (!last) issueA(t + 1, 1);
    BARRIER();
    __builtin_amdgcn_s_setprio(1);
#pragma unroll
    for (int m = 0; m < 4; m++)
#pragma unroll
      for (int n = 0; n < 4; n++) acc[m][n] = MFMA16(aF[m], bF[n], acc[m][n]);
    __builtin_amdgcn_s_setprio(0);
    BARRIER();
    // ---- P2 ----
#pragma unroll
    for (int m = 0; m < 4; m++) aF[m] = *(const bf16x8*)(ab + (arow + (m + 4) * 16) * 32 + laneoff);
    if (!last) issueB(t + 1, 1);
    BARRIER();
    __builtin_amdgcn_s_setprio(1);
#pragma unroll
    for (int m = 0; m < 4; m++)
#pragma unroll
      for (int n = 0; n < 4; n++) acc[m + 4][n] = MFMA16(aF[m], bF[n], acc[m + 4][n]);
    __builtin_amdgcn_s_setprio(0);
    if (last) { WVM(0); } else { WVM(8); }
    BARRIER();
    // ---- P3 ----
#pragma unroll
    for (int m = 0; m < 4; m++) aF[m] = *(const bf16x8*)(ab + 8192 + (arow + m * 16) * 32 + laneoff);
#pragma unroll
    for (int n = 0; n < 4; n++) bF[n] = *(const bf16x8*)(bb2 + 8192 + (brow + n * 16) * 32 + laneoff);
    if (t + 2 < nt) issueA(t + 2, 0);
    BARRIER();
    __builtin_amdgcn_s_setprio(1);
#pragma unroll
    for (int m = 0; m < 4; m++)
#pragma unroll
      for (int n = 0; n < 4; n++) acc[m][n] = MFMA16(aF[m], bF[n], acc[m][n]);
    __builtin_amdgcn_s_setprio(0);
    BARRIER();
    // ---- P4 ----
#pragma unroll
    for (int m = 0; m < 4; m++) aF[m] = *(const bf16x8*)(ab + 8192 + (arow + (m + 4) * 16) * 32 + laneoff);
    if (t + 2 < nt) issueB(t + 2, 0);
    BARRIER();
    __builtin_amdgcn_s_setprio(1);
#pragma unroll
    for (int m = 0; m < 4; m++)
#pragma unroll
      for (int n = 0; n < 4; n++) acc[m + 4][n] = MFMA16(aF[m], bF[n], acc[m + 4][n]);
    __builtin_amdgcn_s_setprio(0);
    if (!last) {
      if (t == nt - 2) { WVM(4); } else { WVM(8); }
    }
    BARRIER();
  }

#pragma unroll
  for (int n = 0; n < 4; n++) {
    const int c = col0 + wn * 64 + n * 16 + l15;
    const float bv = (EPI == 5) ? 0.f : bias[c];
#pragma unroll
    for (int m = 0; m < 8; m++) {
      const int r = row0 + wm * 128 + m * 16 + lh * 4;
#pragma unroll
      for (int j = 0; j < 4; j++) {
        float val = acc[m][n][j] + bv;
        const size_t oi = (size_t)(r + j) * N + c;
        if constexpr (EPI == 0) {
          ((unsigned short*)outp)[oi] = f2bf(val);
        } else if constexpr (EPI == 1) {
          val = 0.5f * val * (1.f + erff(val * 0.70710678118654752f));
          ((unsigned short*)outp)[oi] = f2bf(val);
        } else if constexpr (EPI == 5) {
          ((unsigned short*)outp)[(size_t)z * ((size_t)gridDim.y * 256) * N + oi] = f2bf(val);
        } else {
          ((float*)outp)[oi] = val;
        }
      }
    }
  }
}

// ---------------- pipelined 128xBN GEMM (m97-style, counted vmcnt) ----------------
template <int EPI, int BN, int DEPTH>
__global__ __launch_bounds__(256) void gemmP(const unsigned short* __restrict__ A,
                                             const unsigned short* __restrict__ Bt,
                                             const float* __restrict__ bias,
                                             const float* resid, void* outp,
                                             int K, int N) {
  constexpr int NB = DEPTH + 1;
  constexpr int TILE = (128 + BN) * 32;
  constexpr int NF = BN / 32;
  __shared__ unsigned short lds[NB * TILE];
  const int tid = threadIdx.x;
  const int lane = tid & 63;
  const int w = tid >> 6;
  const int l15 = lane & 15, lh = lane >> 4;
  const int wr = (w >> 1) * 64, wc = (w & 1) * (BN / 2);
  int bx = blockIdx.x, by = blockIdx.y;
  xcd_swz(bx, by);
  const int row0 = by * 128, col0 = bx * BN;

  const unsigned short* gA = A + (size_t)(row0 + (tid >> 2)) * K + (tid & 3) * 8;
  const unsigned short* gB = Bt + (size_t)(col0 + (tid >> 2)) * K + (tid & 3) * 8;
  const size_t rstep = (size_t)64 * K;

  f32x4 acc[4][NF];
#pragma unroll
  for (int m = 0; m < 4; m++)
#pragma unroll
    for (int n = 0; n < NF; n++) acc[m][n] = f32x4{0.f, 0.f, 0.f, 0.f};

  const int nt = K >> 5;

  auto ISSUE = [&](int t) {
    unsigned short* buf = lds + (t % NB) * TILE;
    const unsigned short* a = gA + t * 32;
    GL2LDS(a, buf + tid * 8);
    GL2LDS(a + rstep, buf + 2048 + tid * 8);
    const unsigned short* b = gB + t * 32;
    unsigned short* bb = buf + 128 * 32;
    GL2LDS(b, bb + tid * 8);
    if constexpr (BN == 128) GL2LDS(b + rstep, bb + 2048 + tid * 8);
  };

#pragma unroll
  for (int t = 0; t < DEPTH; t++) ISSUE(t);

  for (int i = 0; i < nt; i++) {
    const int rem = nt - 1 - i;
    if (rem >= DEPTH - 1) {
      if constexpr ((2 + (BN == 128 ? 2 : 1)) * (DEPTH - 1) == 4) WVM(4);
      else WVM(6);
    } else if (DEPTH == 3 && rem == 1) {
      WVM(3);
    } else {
      WVM(0);
    }
    BARRIER();
    const unsigned short* buf = lds + (i % NB) * TILE;
    const unsigned short* rdA = buf + (wr + l15) * 32 + lh * 8;
    const unsigned short* rdB = buf + 128 * 32 + (wc + l15) * 32 + lh * 8;
    bf16x8 aF[4], bF[NF];
#pragma unroll
    for (int m = 0; m < 4; m++) aF[m] = *(const bf16x8*)(rdA + m * 512);
#pragma unroll
    for (int n = 0; n < NF; n++) bF[n] = *(const bf16x8*)(rdB + n * 512);
#pragma unroll
    for (int m = 0; m < 4; m++)
#pragma unroll
      for (int n = 0; n < NF; n++) acc[m][n] = MFMA16(aF[m], bF[n], acc[m][n]);
    if (i + DEPTH < nt) ISSUE(i + DEPTH);
  }

#pragma unroll
  for (int n = 0; n < NF; n++) {
    const int c = col0 + wc + n * 16 + l15;
    const float bv = bias[c];
#pragma unroll
    for (int m = 0; m < 4; m++) {
      const int r = row0 + wr + m * 16 + lh * 4;
#pragma unroll
      for (int j = 0; j < 4; j++) {
        float val = acc[m][n][j] + bv;
        const size_t oi = (size_t)(r + j) * N + c;
        if constexpr (EPI == 0) {
          ((unsigned short*)outp)[oi] = f2bf(val);
        } else if constexpr (EPI == 1) {
          val = 0.5f * val * (1.f + erff(val * 0.70710678118654752f));
          ((unsigned short*)outp)[oi] = f2bf(val);
        } else if constexpr (EPI == 2) {
          ((float*)outp)[oi] = resid[oi] + val;
        } else {
          ((float*)outp)[oi] = val;
        }
      }
    }
  }
}

// ---------------- causal flash attention: QBLK=128, 8 waves, swapped QK^T ----------------
__global__ __launch_bounds__(512) void attn_kernel(const unsigned short* __restrict__ qkv,
                                                   unsigned short* __restrict__ o) {
  __shared__ unsigned short Ks[2][64 * 72];
  __shared__ unsigned short Vts[2][64 * 72];
  __shared__ unsigned short Ps[8][16 * 72];
  const int tid = threadIdx.x;
  const int lane = tid & 63, w = tid >> 6;
  const int l15 = lane & 15, lh = lane >> 4;
  const int qt = gridDim.x - 1 - blockIdx.x;
  const int bh = blockIdx.y;
  const int b = bh >> 4, h = bh & 15;
  const int rb = b * T_;
  const int q0 = qt * 128;
  const int nkt = 2 * qt + 2;

  bf16x8 qf[2];
  {
    const unsigned short* qp = qkv + (size_t)(rb + q0 + w * 16 + l15) * 3072 + h * 64 + lh * 8;
    qf[0] = *(const bf16x8*)qp;
    qf[1] = *(const bf16x8*)(qp + 32);
#pragma unroll
    for (int e = 0; e < 2; e++) {
      u16x8 u = __builtin_bit_cast(u16x8, qf[e]);
#pragma unroll
      for (int j = 0; j < 8; j++) u[j] = f2bf(bf2f(u[j]) * 0.1803368801111832f);
      qf[e] = __builtin_bit_cast(bf16x8, u);
    }
  }
  f32x4 oa[4];
  float mrun = -1e30f, lrun = 0.f;
#pragma unroll
  for (int n = 0; n < 4; n++) oa[n] = f32x4{0.f, 0.f, 0.f, 0.f};

  const int qrow = q0 + w * 16 + l15;

  u16x8 kreg, vreg;
  auto loadKV = [&](int kt) {
    kreg = *(const u16x8*)(qkv + (size_t)(rb + kt * 64 + (tid >> 3)) * 3072 + 1024 + h * 64 +
                           (tid & 7) * 8);
    vreg = *(const u16x8*)(qkv + (size_t)(rb + kt * 64 + lane) * 3072 + 2048 + h * 64 + w * 8);
  };
  auto writeKV = [&](int kt) {
    const int bs = kt & 1;
    *(u16x8*)&Ks[bs][(tid >> 3) * 72 + (tid & 7) * 8] = kreg;
#pragma unroll
    for (int j = 0; j < 8; j++) Vts[bs][(w * 8 + j) * 72 + lane] = vreg[j];
  };

  loadKV(0);
  WVM(0);
  writeKV(0);
  loadKV(1);
  WLG();
  BARRIER();

  for (int kt = 0; kt < nkt; ++kt) {
    const int bs = kt & 1;
    f32x4 sa[4];
#pragma unroll
    for (int n = 0; n < 4; n++) sa[n] = f32x4{0.f, 0.f, 0.f, 0.f};
    __builtin_amdgcn_s_setprio(1);
#pragma unroll
    for (int ke = 0; ke < 2; ke++) {
#pragma unroll
      for (int n = 0; n < 4; n++) {
        const bf16x8 kf = *(const bf16x8*)&Ks[bs][(n * 16 + l15) * 72 + ke * 32 + lh * 8];
        sa[n] = MFMA16(kf, qf[ke], sa[n]);
      }
    }
    __builtin_amdgcn_s_setprio(0);
    float sv[4][4];
    const bool diag = (kt >= 2 * qt);
#pragma unroll
    for (int n = 0; n < 4; n++)
#pragma unroll
      for (int j = 0; j < 4; j++) {
        float v = sa[n][j];
        if (diag && (kt * 64 + n * 16 + lh * 4 + j) > qrow) v = -1e30f;
        sv[n][j] = v;
      }
    float mx = sv[0][0];
#pragma unroll
    for (int n = 0; n < 4; n++)
#pragma unroll
      for (int j = 0; j < 4; j++) mx = fmaxf(mx, sv[n][j]);
    mx = fmaxf(mx, __shfl_xor(mx, 16));
    mx = fmaxf(mx, __shfl_xor(mx, 32));
    const bool small = (mx - mrun <= 8.f);
    if (!__all(small)) {
      const float m2 = fmaxf(mrun, mx);
      const float corr = exp2f(mrun - m2);
      mrun = m2;
      lrun *= corr;
      float cO[4];
#pragma unroll
      for (int j = 0; j < 4; j++) cO[j] = __shfl(corr, lh * 4 + j);
#pragma unroll
      for (int n = 0; n < 4; n++)
#pragma unroll
        for (int j = 0; j < 4; j++) oa[n][j] *= cO[j];
    }
    float rs = 0.f;
#pragma unroll
    for (int n = 0; n < 4; n++) {
      u16x4 pk;
#pragma unroll
      for (int j = 0; j < 4; j++) {
        const float p = exp2f(sv[n][j] - mrun);
        rs += p;
        pk[j] = f2bf(p);
      }
      *(u16x4*)&Ps[w][l15 * 72 + n * 16 + lh * 4] = pk;
    }
    rs += __shfl_xor(rs, 16);
    rs += __shfl_xor(rs, 32);
    lrun += rs;
    __builtin_amdgcn_s_setprio(1);
#pragma unroll
    for (int ks = 0; ks < 2; ks++) {
      const bf16x8 pf = *(const bf16x8*)&Ps[w][l15 * 72 + ks * 32 + lh * 8];
#pragma unroll
      for (int n = 0; n < 4; n++) {
        const bf16x8 vf = *(const bf16x8*)&Vts[bs][(n * 16 + l15) * 72 + ks * 32 + lh * 8];
        oa[n] = MFMA16(pf, vf, oa[n]);
      }
    }
    __builtin_amdgcn_s_setprio(0);
    if (kt + 1 < nkt) {
      WVM(0);
      writeKV(kt + 1);
      if (kt + 2 < nkt) loadKV(kt + 2);
      WLG();
      BARRIER();
    }
  }
  float linv[4];
#pragma unroll
  for (int j = 0; j < 4; j++) linv[j] = 1.f / __shfl(lrun, lh * 4 + j);
#pragma unroll
  for (int n = 0; n < 4; n++)
#pragma unroll
    for (int j = 0; j < 4; j++) {
      o[(size_t)(rb + q0 + w * 16 + lh * 4 + j) * D_ + h * 64 + n * 16 + l15] =
          f2bf(oa[n][j] * linv[j]);
    }
}

// ---------------- host orchestration ----------------
extern "C" void kernel_launch(void* const* d_in, const int* in_sizes, int n_in,
                              void* d_out, int out_size, void* d_ws, size_t ws_size,
                              hipStream_t stream) {
  const int* idx = (const int*)d_in[0];
  const float* tk = (const float*)d_in[1];
  const float* pe = (const float*)d_in[2];
  const float* ln1g = (const float*)d_in[3];
  const float* ln1b = (const float*)d_in[4];
  const float* Wq = (const float*)d_in[5];
  const float* bq = (const float*)d_in[6];
  const float* Wk = (const float*)d_in[7];
  const float* bk = (const float*)d_in[8];
  const float* Wv = (const float*)d_in[9];
  const float* bv = (const float*)d_in[10];
  const float* Wo = (const float*)d_in[11];
  const float* bo = (const float*)d_in[12];
  const float* ln2g = (const float*)d_in[13];
  const float* ln2b = (const float*)d_in[14];
  const float* W1 = (const float*)d_in[15];
  const float* b1 = (const float*)d_in[16];
  const float* W2 = (const float*)d_in[17];
  const float* b2 = (const float*)d_in[18];
  const float* lnfg = (const float*)d_in[19];
  const float* lnfb = (const float*)d_in[20];
  const float* Wout = (const float*)d_in[21];
  const float* bout = (const float*)d_in[22];

  char* ws = (char*)d_ws;
  size_t off = 0;
  auto alloc = [&](size_t bytes) {
    void* p = ws + off;
    off += (bytes + 255) & ~(size_t)255;
    return p;
  };
  unsigned short* wqkv = (unsigned short*)alloc(12ull * 3072 * 1024 * 2);
  unsigned short* wo = (unsigned short*)alloc(12ull * 1024 * 1024 * 2);
  unsigned short* w1 = (unsigned short*)alloc(12ull * 4096 * 1024 * 2);
  unsigned short* w2 = (unsigned short*)alloc(12ull * 4096 * 1024 * 2);
  unsigned short* wout = (unsigned short*)alloc(8192ull * 1024 * 2);
  float* bqkv = (float*)alloc(12ull * 3072 * 4);
  float* x = (float*)alloc(4096ull * 1024 * 4);
  unsigned short* hb = (unsigned short*)alloc(4096ull * 1024 * 2);
  unsigned short* qkvb = (unsigned short*)alloc(4096ull * 3072 * 2);
  unsigned short* ob = (unsigned short*)alloc(4096ull * 1024 * 2);
  unsigned short* ub = (unsigned short*)alloc(4096ull * 4096 * 2);
  unsigned short* part = (unsigned short*)alloc(4ull * 4096 * 1024 * 2);

  TpArgs ta;
  ta.seg[0] = {Wo, wo, 1024, 1024, 1048576, 1048576, 8, 8, 768};
  ta.seg[1] = {W1, w1, 1024, 4096, 4194304, 4194304, 32, 8, 3072};
  ta.seg[2] = {W2, w2, 4096, 1024, 4194304, 4194304, 8, 32, 3072};
  ta.seg[3] = {Wout, wout, 1024, 8192, 0, 0, 64, 8, 512};
  tpose4_kernel<<<7424, 256, 0, stream>>>(ta);
  qkv_tpose_kernel<<<2316, 256, 0, stream>>>(Wq, Wk, Wv, bq, bk, bv, wqkv, bqkv);
  embed_ln_kernel<<<4096, 256, 0, stream>>>(idx, tk, pe, ln1g, ln1b, x, hb);

  for (int l = 0; l < 12; l++) {
    gemm256<0><<<dim3(12, 16), 512, 0, stream>>>(hb, wqkv + (size_t)l * 3145728,
                                                 bqkv + l * 3072, qkvb, 1024, 1024, 3072);
    attn_kernel<<<dim3(8, 64), 512, 0, stream>>>(qkvb, ob);
    gemmP<2, 64, 3><<<dim3(16, 32), 256, 0, stream>>>(ob, wo + (size_t)l * 1048576,
                                                      bo + l * 1024, x, x, 1024, 1024);
    ln_kernel<<<4096, 256, 0, stream>>>(x, ln2g + l * 1024, ln2b + l * 1024, hb);
    gemm256<1><<<dim3(16, 16), 512, 0, stream>>>(hb, w1 + (size_t)l * 4194304,
                                                 b1 + l * 4096, ub, 1024, 1024, 4096);
    gemm256<5><<<dim3(4, 16, 4), 512, 0, stream>>>(ub, w2 + (size_t)l * 4194304,
                                                   nullptr, part, 1024, 4096, 1024);
    const float* ng = (l < 11) ? (ln1g + (l + 1) * 1024) : lnfg;
    const float* nb = (l < 11) ? (ln1b + (l + 1) * 1024) : lnfb;
    redk_ln_kernel<<<4096, 256, 0, stream>>>(part, b2 + l * 1024, x, ng, nb, hb);
  }
  gemmP<3, 128, 2><<<dim3(64, 32), 256, 0, stream>>>(hb, wout, bout, nullptr, d_out, 1024, 8192);
}